// Round 9
// baseline (186.711 us; speedup 1.0000x reference)
//
#include <hip/hip_runtime.h>
#include <hip/hip_bf16.h>
#include <math.h>

#define NEGV (-1e10f)

typedef __attribute__((ext_vector_type(8))) short bf16x8;
typedef __attribute__((ext_vector_type(4))) float f32x4;
typedef __attribute__((ext_vector_type(16))) float f32x16;

static __device__ __forceinline__ unsigned short f2bf(float f) {
  unsigned int u = __builtin_bit_cast(unsigned int, f);
  unsigned int r = (u + 0x7fffu + ((u >> 16) & 1u)) >> 16;
  return (unsigned short)r;
}
static __device__ __forceinline__ float bf2f(unsigned short v) {
  return __builtin_bit_cast(float, (unsigned int)v << 16);
}

#define GLD16(g, l)                                                   \
  __builtin_amdgcn_global_load_lds(                                   \
      (const __attribute__((address_space(1))) void*)(g),             \
      (__attribute__((address_space(3))) void*)(l), 16, 0, 0)

// ---------------------------------------------------------------------------
// K1: merged input casts. Blocks [0,2048): emb fp32->bf16 + attn-weight
// logits. Blocks [2048,3776): weight matrices fp32->bf16. For z in {0,1}
// (W_q, W_k) rows are PERMUTED: feature f=(h,d) stored at row
// o = (d/16)*128 + ((d%16)/8)*64 + (d%4)*16 + (((d%8)/4))*8 + h, so the GEMM
// epilogue's per-thread elems are contiguous (b64 LDS writes). Since the same
// permutation applies to Q and K, QK^T per head is invariant.
// ---------------------------------------------------------------------------
__global__ __launch_bounds__(256) void cast_inputs(
    const float* __restrict__ emb, const int* __restrict__ tags,
    const float* __restrict__ ww, const float* __restrict__ wq,
    const float* __restrict__ wk, const float* __restrict__ wv,
    unsigned short* __restrict__ embbf, float* __restrict__ logits,
    unsigned short* __restrict__ wbf) {
  int bx = blockIdx.x;
  if (bx < 2048) {
    int w = threadIdx.x >> 6, lane = threadIdx.x & 63;
    int row = bx * 4 + w;  // 0..8191
    const float4* src = (const float4*)(emb + (size_t)row * 768);
    const float4* wsrc = (const float4*)ww;
    ushort4* dst = (ushort4*)(embbf + (size_t)row * 768);
    float d = 0.f;
#pragma unroll
    for (int j = 0; j < 3; j++) {
      int idx = lane + 64 * j;
      float4 v = src[idx];
      float4 wv = wsrc[idx];
      d += v.x * wv.x + v.y * wv.y + v.z * wv.z + v.w * wv.w;
      ushort4 o;
      o.x = f2bf(v.x); o.y = f2bf(v.y); o.z = f2bf(v.z); o.w = f2bf(v.w);
      dst[idx] = o;
    }
#pragma unroll
    for (int off = 32; off; off >>= 1) d += __shfl_xor(d, off);
    if (lane == 0) logits[row] = (tags[row] == 0) ? NEGV : d;
  } else {
    int g = bx - 2048;              // 0..1727
    int z = g / 576;                // matrix
    int idx = (g - z * 576) * 256 + threadIdx.x;  // float4 index
    const float* src = (z == 0) ? wq : (z == 1) ? wk : wv;
    float4 v = ((const float4*)src)[idx];
    ushort4 o;
    o.x = f2bf(v.x); o.y = f2bf(v.y); o.z = f2bf(v.z); o.w = f2bf(v.w);
    if (z == 2) {
      ((ushort4*)(wbf + (size_t)z * 589824))[idx] = o;
    } else {
      int f = idx / 192;            // source feature row
      int col4 = idx - f * 192;
      int h = f & 7, dg = f >> 3;   // head, depth 0..95
      int tt = dg >> 4, ddl = dg & 15;
      int wn = ddl >> 3, cb = (ddl >> 2) & 1, j = ddl & 3;
      int orow = tt * 128 + wn * 64 + j * 16 + cb * 8 + h;
      ((ushort4*)(wbf + (size_t)z * 589824))[orow * 192 + col4] = o;
    }
  }
}

// ---------------------------------------------------------------------------
// K2: softmax over s=1024 per batch of the masked logits -> aw
// ---------------------------------------------------------------------------
__global__ __launch_bounds__(256) void softmax_aw(
    const float* __restrict__ logits, float* __restrict__ aw) {
  __shared__ float red[4];
  int b = blockIdx.x, t = threadIdx.x;
  const float* L = logits + b * 1024;
  float x0 = L[t], x1 = L[t + 256], x2 = L[t + 512], x3 = L[t + 768];
  float m = fmaxf(fmaxf(x0, x1), fmaxf(x2, x3));
#pragma unroll
  for (int off = 32; off; off >>= 1) m = fmaxf(m, __shfl_xor(m, off));
  if ((t & 63) == 0) red[t >> 6] = m;
  __syncthreads();
  m = fmaxf(fmaxf(red[0], red[1]), fmaxf(red[2], red[3]));
  float e0 = __expf(x0 - m), e1 = __expf(x1 - m), e2 = __expf(x2 - m),
        e3 = __expf(x3 - m);
  float s = e0 + e1 + e2 + e3;
#pragma unroll
  for (int off = 32; off; off >>= 1) s += __shfl_xor(s, off);
  __syncthreads();
  if ((t & 63) == 0) red[t >> 6] = s;
  __syncthreads();
  float inv = 1.0f / (red[0] + red[1] + red[2] + red[3]);
  float* A = aw + b * 1024;
  A[t] = e0 * inv; A[t + 256] = e1 * inv;
  A[t + 512] = e2 * inv; A[t + 768] = e3 * inv;
}

// ---------------------------------------------------------------------------
// K3: QKV projection GEMM. 128x128 tile, BK=32, global_load_lds width=16,
// prefetch-ahead dbuf, one barrier per K-iter.
// Q/K epilogue: thanks to the W row-perm (K1), thread elems are contiguous ->
// ds_write_b64 (was the b16-scatter conflict source). V epilogue: LDS
// row-major repack (stride 136 for 16B align) -> coalesced b128 stores.
// 32x32-fragment layout: chunk = ((b*32+q/32)*8+h)*6 + k/16 (1KB chunks),
// in-chunk lane32 = (q%32)|(((k%16)>>3)<<5), elem = k%8 (k = permuted d).
// ---------------------------------------------------------------------------
__global__ __launch_bounds__(256) void qkv_gemm(
    const unsigned short* __restrict__ A, const unsigned short* __restrict__ Wbf,
    unsigned short* __restrict__ Qf, unsigned short* __restrict__ Kf,
    unsigned short* __restrict__ Vbf) {
  // union: staging 2x(128x32)x2 = 16384 shorts / Q-K repack 32x520 = 16640 /
  // V repack 128x136 = 17408
  __shared__ __align__(16) unsigned short sm[17408];
  unsigned short* As = sm;         // dbuf: As + buf*4096
  unsigned short* Bs = sm + 8192;  // dbuf: Bs + buf*4096
  int z = blockIdx.z;
  const unsigned short* B = Wbf + (size_t)z * 589824;
  int mb = blockIdx.x * 128, nb = blockIdx.y * 128;
  int tid = threadIdx.x;
  int w = tid >> 6, lane = tid & 63;
  int wm = w >> 1, wn = w & 1;
  int c = lane & 15, quad = lane >> 4;
  int lrow = lane >> 2;
  int lcol = ((lane & 3) ^ (lrow & 3)) * 8;  // XOR-swizzled source chunk
  const unsigned short* Ag = A + (size_t)(mb + w * 32 + lrow) * 768 + lcol;
  const unsigned short* Bg = B + (size_t)(nb + w * 32 + lrow) * 768 + lcol;
  int woff = w * 1024;

#define PREFETCH(buf, kb)                                              \
  do {                                                                 \
    GLD16(Ag + (kb), As + (buf) * 4096 + woff);                        \
    GLD16(Ag + (kb) + 16 * 768, As + (buf) * 4096 + woff + 512);       \
    GLD16(Bg + (kb), Bs + (buf) * 4096 + woff);                        \
    GLD16(Bg + (kb) + 16 * 768, Bs + (buf) * 4096 + woff + 512);       \
  } while (0)

  f32x4 acc[4][4];
#pragma unroll
  for (int i = 0; i < 4; i++)
#pragma unroll
    for (int j = 0; j < 4; j++) acc[i][j] = 0;

  PREFETCH(0, 0);
  for (int it = 0; it < 24; it++) {
    __syncthreads();
    if (it + 1 < 24) PREFETCH((it + 1) & 1, (it + 1) * 32);
    const unsigned short* Ab = As + (it & 1) * 4096;
    const unsigned short* Bb = Bs + (it & 1) * 4096;
    int sw = (quad ^ (c & 3)) * 8;  // swizzled chunk offset for k-chunk `quad`
    bf16x8 af[4], bfr[4];
#pragma unroll
    for (int i = 0; i < 4; i++)
      af[i] = *(const bf16x8*)&Ab[(wm * 64 + i * 16 + c) * 32 + sw];
#pragma unroll
    for (int j = 0; j < 4; j++)
      bfr[j] = *(const bf16x8*)&Bb[(wn * 64 + j * 16 + c) * 32 + sw];
#pragma unroll
    for (int i = 0; i < 4; i++)
#pragma unroll
      for (int j = 0; j < 4; j++)
        acc[i][j] = __builtin_amdgcn_mfma_f32_16x16x32_bf16(af[i], bfr[j],
                                                            acc[i][j], 0, 0, 0);
  }
  __syncthreads();  // staging reads done before epilogue reuses sm

  // C row = mb+wm*64+i*16+quad*4+r, col = nb+wn*64+j*16+c
  if (z == 2) {
    // scatter into sm row-major [128][136], then coalesced b128 stores
#pragma unroll
    for (int i = 0; i < 4; i++)
#pragma unroll
      for (int j = 0; j < 4; j++)
#pragma unroll
        for (int r = 0; r < 4; r++) {
          int rl = wm * 64 + i * 16 + quad * 4 + r;
          int cl = wn * 64 + j * 16 + c;
          sm[rl * 136 + cl] = f2bf(acc[i][j][r]);
        }
    __syncthreads();
#pragma unroll
    for (int it2 = 0; it2 < 8; it2++) {
      int g2 = it2 * 256 + tid;  // 0..2047, 16B units (128 rows x 16)
      int rl = g2 >> 4;
      int cu = (g2 & 15) * 8;
      bf16x8 vdat = *(const bf16x8*)&sm[rl * 136 + cu];
      *(bf16x8*)&Vbf[(size_t)(mb + rl) * 768 + nb + cu] = vdat;
    }
  } else {
    unsigned short* O = (z == 0) ? Qf : Kf;
    // col o holds permuted feature with h = c&7, elem = 4*(c>>3)+j ->
    // thread's 4 j-values are contiguous shorts: one b64 per (i,r).
#pragma unroll
    for (int i = 0; i < 4; i++) {
#pragma unroll
      for (int r = 0; r < 4; r++) {
        int qlr = wm * 64 + i * 16 + quad * 4 + r;  // 0..127
        int chunkL = (qlr >> 5) * 8 + (c & 7);      // 0..31
        int lane32 = (qlr & 31) + wn * 32;
        ushort4 pk;
        pk.x = f2bf(acc[i][0][r]);
        pk.y = f2bf(acc[i][1][r]);
        pk.z = f2bf(acc[i][2][r]);
        pk.w = f2bf(acc[i][3][r]);
        *(ushort4*)&sm[chunkL * 520 + lane32 * 8 + 4 * (c >> 3)] = pk;
      }
    }
    __syncthreads();
    int bq = mb >> 10;
    int qt32g0 = (mb & 1023) >> 5;
    int tt = blockIdx.y;  // d/16 chunk (0..5)
#pragma unroll
    for (int it2 = 0; it2 < 8; it2++) {
      int g = it2 * 256 + tid;
      int chunkL = g >> 6;
      int off = (g & 63) * 8;
      bf16x8 vdat = *(const bf16x8*)&sm[chunkL * 520 + off];
      int qt32 = qt32g0 + (chunkL >> 3), h = chunkL & 7;
      size_t dst = ((((size_t)(bq * 32 + qt32) * 8 + h) * 6 + tt) << 9) + off;
      *(bf16x8*)&O[dst] = vdat;
    }
  }
#undef PREFETCH
}

// ---------------------------------------------------------------------------
// K4: attention. 512-thread block = 64q x 128k x 8h; 8 waves = 2(wq) x 4(wk)
// of 32x32 tiles (mfma_f32_32x32x16_bf16). Q-slab (64q full: 96KB) staged in
// LDS ONCE (single barrier), K fragments direct global->VGPR; h-loop is
// barrier-free. h-softmax without max-shift (|logit*C2| << 126).
// grid (8 kb, 16 qb, 8 b) = 1024 blocks.
// ---------------------------------------------------------------------------
__global__ __launch_bounds__(512) void attn(
    const unsigned short* __restrict__ Qf, const unsigned short* __restrict__ Kf,
    const float* __restrict__ aw, float* __restrict__ Ptp) {
  __shared__ __align__(16) unsigned short Qs[49152];  // 96 x 1KB chunks
  __shared__ float pbuf[2048];  // (wq*4+wk)*256 + kcol*8 + h
  int b = blockIdx.z, qb = blockIdx.y, kb = blockIdx.x;
  int tid = threadIdx.x, w = tid >> 6, lane = tid & 63;
  int wq2 = w >> 2, wk2 = w & 3;

  // stage Q: 96 chunks, wave w takes chunk call*8+w (wave-uniform LDS base)
#pragma unroll
  for (int call = 0; call < 12; call++) {
    int cc = call * 8 + w;  // 0..95
    int q32 = cc / 48, rem = cc - q32 * 48;
    size_t src =
        ((size_t)((b * 32 + qb * 2 + q32) * 48 + rem) << 9) + (size_t)lane * 8;
    GLD16(Qf + src, Qs + cc * 512);
  }
  __syncthreads();

  const unsigned short* Kc =
      Kf + ((size_t)(b * 32 + kb * 4 + wk2) * 48 << 9) + (size_t)lane * 8;
  const unsigned short* Qw = Qs + wq2 * 48 * 512 + (size_t)lane * 8;

  f32x16 acc[8];
#pragma unroll
  for (int h = 0; h < 8; h++) acc[h] = 0;
#pragma unroll
  for (int h = 0; h < 8; h++) {
#pragma unroll
    for (int t = 0; t < 6; t++) {
      bf16x8 a = *(const bf16x8*)(Qw + (size_t)(h * 6 + t) * 512);
      bf16x8 bb = *(const bf16x8*)(Kc + (size_t)(h * 6 + t) * 512);
      acc[h] = __builtin_amdgcn_mfma_f32_32x32x16_bf16(a, bb, acc[h], 0, 0, 0);
    }
  }

  // softmax over h per (q,k); C/D: col=lane&31 (k), row=(reg&3)+8*(reg>>2)+4*(lane>>5)
  float awv[16];
#pragma unroll
  for (int reg = 0; reg < 16; reg++) {
    int row = (reg & 3) + 8 * (reg >> 2) + 4 * (lane >> 5);
    awv[reg] = aw[b * 1024 + qb * 64 + wq2 * 32 + row];
  }
  float partial[8];
#pragma unroll
  for (int h = 0; h < 8; h++) partial[h] = 0.f;
  const float C2 = 0.10206207261596577f * 1.4426950408889634f;  // /sqrt(96)*log2e
#pragma unroll
  for (int reg = 0; reg < 16; reg++) {
    float v[8];
    float ssum = 0.f;
#pragma unroll
    for (int h = 0; h < 8; h++) {
      float e = exp2f(acc[h][reg] * C2);  // no max-shift needed
      v[h] = e;
      ssum += e;
    }
    float g = awv[reg] * __builtin_amdgcn_rcpf(ssum);  // aw==0 for padded q
#pragma unroll
    for (int h = 0; h < 8; h++) partial[h] += v[h] * g;
  }
#pragma unroll
  for (int h = 0; h < 8; h++) {
    float v = partial[h];
    v += __shfl_xor(v, 32);  // combine q-row halves -> full 32-q sum per col
    partial[h] = v;
  }
  if (lane < 32) {
#pragma unroll
    for (int h = 0; h < 8; h++) pbuf[w * 256 + lane * 8 + h] = partial[h];
  }
  __syncthreads();
  // combine wq2 halves: rows w and w+4; 1024 outputs, 512 threads x 2
#pragma unroll
  for (int half = 0; half < 2; half++) {
    int idx = half * 512 + tid;
    int wko = idx >> 8, rem2 = idx & 255;
    float s = pbuf[wko * 256 + rem2] + pbuf[(wko + 4) * 256 + rem2];
    int kcol = rem2 >> 3, h = rem2 & 7;
    Ptp[(((size_t)qb * 8 + b) * 1024 + kb * 128 + wko * 32 + kcol) * 8 + h] = s;
  }
}

// ---------------------------------------------------------------------------
// K5: out[b,o] = sum_k (sum_qb Ptp[qb][b][k][o&7]) * V[b,k,o]   (V bf16)
// grid (32 kc, 8 b); threads 0..191 each own 4 consecutive o (ushort4 loads)
// ---------------------------------------------------------------------------
__global__ __launch_bounds__(256) void finalize(
    const float* __restrict__ Ptp, const unsigned short* __restrict__ Vbf,
    float* __restrict__ out) {
  __shared__ float ps[256];  // 32 k x 8 h
  int kc = blockIdx.x, b = blockIdx.y;
  int t = threadIdx.x;
  {
    int k = kc * 32 + (t >> 3), h = t & 7;
    float s = 0.f;
#pragma unroll
    for (int qc = 0; qc < 16; qc++)
      s += Ptp[(((size_t)qc * 8 + b) * 1024 + k) * 8 + h];
    ps[t] = s;
  }
  __syncthreads();
  if (t < 192) {
    int o0 = t * 4;
    int hb = o0 & 7;  // 0 or 4
    float a0 = 0, a1 = 0, a2 = 0, a3 = 0;
    const unsigned short* Vb = Vbf + ((size_t)b * 1024 + kc * 32) * 768 + o0;
#pragma unroll 4
    for (int kk = 0; kk < 32; kk++) {
      ushort4 vv = *(const ushort4*)(Vb + (size_t)kk * 768);
      const float* p = &ps[kk * 8 + hb];
      a0 += p[0] * bf2f(vv.x);
      a1 += p[1] * bf2f(vv.y);
      a2 += p[2] * bf2f(vv.z);
      a3 += p[3] * bf2f(vv.w);
    }
    atomicAdd(&out[b * 768 + o0], a0);
    atomicAdd(&out[b * 768 + o0 + 1], a1);
    atomicAdd(&out[b * 768 + o0 + 2], a2);
    atomicAdd(&out[b * 768 + o0 + 3], a3);
  }
}

// ---------------------------------------------------------------------------
extern "C" void kernel_launch(void* const* d_in, const int* in_sizes, int n_in,
                              void* d_out, int out_size, void* d_ws,
                              size_t ws_size, hipStream_t stream) {
  const float* emb = (const float*)d_in[0];
  const int* tags = (const int*)d_in[1];
  const float* ww = (const float*)d_in[2];
  const float* wq = (const float*)d_in[3];
  const float* wk = (const float*)d_in[4];
  const float* wv = (const float*)d_in[5];
  float* out = (float*)d_out;
  char* ws = (char*)d_ws;
  unsigned short* embbf = (unsigned short*)(ws + 0);           // 12,582,912
  unsigned short* wbf   = (unsigned short*)(ws + 12582912);    //  3,538,944
  unsigned short* Qf    = (unsigned short*)(ws + 16121856);    // 12,582,912
  unsigned short* Kf    = (unsigned short*)(ws + 28704768);    // 12,582,912
  unsigned short* Vbf   = (unsigned short*)(ws + 41287680);    // 12,582,912
  float* logits         = (float*)(ws + 53870592);             //     32,768
  float* aw             = (float*)(ws + 53903360);             //     32,768
  float* Ptp            = (float*)(ws + 53936128);             //  4,194,304

  hipMemsetAsync(out, 0, 8 * 768 * sizeof(float), stream);
  cast_inputs<<<3776, 256, 0, stream>>>(emb, tags, ww, wq, wk, wv, embbf,
                                        logits, wbf);
  softmax_aw<<<8, 256, 0, stream>>>(logits, aw);
  qkv_gemm<<<dim3(64, 6, 3), 256, 0, stream>>>(embbf, wbf, Qf, Kf, Vbf);
  attn<<<dim3(8, 16, 8), 512, 0, stream>>>(Qf, Kf, aw, Ptp);
  finalize<<<dim3(32, 8), 256, 0, stream>>>(Ptp, Vbf, out);
}

// Round 10
// 171.068 us; speedup vs baseline: 1.0914x; 1.0914x over previous
//
#include <hip/hip_runtime.h>
#include <hip/hip_bf16.h>
#include <math.h>

#define NEGV (-1e10f)

typedef __attribute__((ext_vector_type(8))) short bf16x8;
typedef __attribute__((ext_vector_type(4))) float f32x4;
typedef __attribute__((ext_vector_type(16))) float f32x16;

static __device__ __forceinline__ unsigned short f2bf(float f) {
  unsigned int u = __builtin_bit_cast(unsigned int, f);
  unsigned int r = (u + 0x7fffu + ((u >> 16) & 1u)) >> 16;
  return (unsigned short)r;
}
static __device__ __forceinline__ float bf2f(unsigned short v) {
  return __builtin_bit_cast(float, (unsigned int)v << 16);
}

#define GLD16(g, l)                                                   \
  __builtin_amdgcn_global_load_lds(                                   \
      (const __attribute__((address_space(1))) void*)(g),             \
      (__attribute__((address_space(3))) void*)(l), 16, 0, 0)

// ---------------------------------------------------------------------------
// K1: merged input casts. Blocks [0,2048): emb fp32->bf16 + attn-weight
// logits. Blocks [2048,3776): weight matrices fp32->bf16. W_q/W_k rows are
// PERMUTED (same perm on both -> QK^T invariant) so the GEMM epilogue's
// per-thread elems are contiguous (b64 LDS writes).
// ---------------------------------------------------------------------------
__global__ __launch_bounds__(256) void cast_inputs(
    const float* __restrict__ emb, const int* __restrict__ tags,
    const float* __restrict__ ww, const float* __restrict__ wq,
    const float* __restrict__ wk, const float* __restrict__ wv,
    unsigned short* __restrict__ embbf, float* __restrict__ logits,
    unsigned short* __restrict__ wbf) {
  int bx = blockIdx.x;
  if (bx < 2048) {
    int w = threadIdx.x >> 6, lane = threadIdx.x & 63;
    int row = bx * 4 + w;  // 0..8191
    const float4* src = (const float4*)(emb + (size_t)row * 768);
    const float4* wsrc = (const float4*)ww;
    ushort4* dst = (ushort4*)(embbf + (size_t)row * 768);
    float d = 0.f;
#pragma unroll
    for (int j = 0; j < 3; j++) {
      int idx = lane + 64 * j;
      float4 v = src[idx];
      float4 wv = wsrc[idx];
      d += v.x * wv.x + v.y * wv.y + v.z * wv.z + v.w * wv.w;
      ushort4 o;
      o.x = f2bf(v.x); o.y = f2bf(v.y); o.z = f2bf(v.z); o.w = f2bf(v.w);
      dst[idx] = o;
    }
#pragma unroll
    for (int off = 32; off; off >>= 1) d += __shfl_xor(d, off);
    if (lane == 0) logits[row] = (tags[row] == 0) ? NEGV : d;
  } else {
    int g = bx - 2048;              // 0..1727
    int z = g / 576;                // matrix
    int idx = (g - z * 576) * 256 + threadIdx.x;  // float4 index
    const float* src = (z == 0) ? wq : (z == 1) ? wk : wv;
    float4 v = ((const float4*)src)[idx];
    ushort4 o;
    o.x = f2bf(v.x); o.y = f2bf(v.y); o.z = f2bf(v.z); o.w = f2bf(v.w);
    if (z == 2) {
      ((ushort4*)(wbf + (size_t)z * 589824))[idx] = o;
    } else {
      int f = idx / 192;            // source feature row
      int col4 = idx - f * 192;
      int h = f & 7, dg = f >> 3;   // head, depth 0..95
      int tt = dg >> 4, ddl = dg & 15;
      int wn = ddl >> 3, cb = (ddl >> 2) & 1, j = ddl & 3;
      int orow = tt * 128 + wn * 64 + j * 16 + cb * 8 + h;
      ((ushort4*)(wbf + (size_t)z * 589824))[orow * 192 + col4] = o;
    }
  }
}

// ---------------------------------------------------------------------------
// K2: softmax over s=1024 per batch of the masked logits -> aw
// ---------------------------------------------------------------------------
__global__ __launch_bounds__(256) void softmax_aw(
    const float* __restrict__ logits, float* __restrict__ aw) {
  __shared__ float red[4];
  int b = blockIdx.x, t = threadIdx.x;
  const float* L = logits + b * 1024;
  float x0 = L[t], x1 = L[t + 256], x2 = L[t + 512], x3 = L[t + 768];
  float m = fmaxf(fmaxf(x0, x1), fmaxf(x2, x3));
#pragma unroll
  for (int off = 32; off; off >>= 1) m = fmaxf(m, __shfl_xor(m, off));
  if ((t & 63) == 0) red[t >> 6] = m;
  __syncthreads();
  m = fmaxf(fmaxf(red[0], red[1]), fmaxf(red[2], red[3]));
  float e0 = __expf(x0 - m), e1 = __expf(x1 - m), e2 = __expf(x2 - m),
        e3 = __expf(x3 - m);
  float s = e0 + e1 + e2 + e3;
#pragma unroll
  for (int off = 32; off; off >>= 1) s += __shfl_xor(s, off);
  __syncthreads();
  if ((t & 63) == 0) red[t >> 6] = s;
  __syncthreads();
  float inv = 1.0f / (red[0] + red[1] + red[2] + red[3]);
  float* A = aw + b * 1024;
  A[t] = e0 * inv; A[t + 256] = e1 * inv;
  A[t + 512] = e2 * inv; A[t + 768] = e3 * inv;
}

// ---------------------------------------------------------------------------
// K3: QKV projection GEMM (R9 version, kept). 128x128 tile, BK=32,
// global_load_lds width=16, prefetch-ahead dbuf, one barrier per K-iter.
// Q/K epilogue: b64 LDS writes (W row-perm). V epilogue: LDS repack ->
// coalesced b128 stores.
// 32x32-fragment layout: chunk = ((b*32+q/32)*8+h)*6 + k/16 (1KB chunks),
// in-chunk lane32 = (q%32)|(((k%16)>>3)<<5), elem = k%8 (k = permuted d).
// ---------------------------------------------------------------------------
__global__ __launch_bounds__(256) void qkv_gemm(
    const unsigned short* __restrict__ A, const unsigned short* __restrict__ Wbf,
    unsigned short* __restrict__ Qf, unsigned short* __restrict__ Kf,
    unsigned short* __restrict__ Vbf) {
  __shared__ __align__(16) unsigned short sm[17408];
  unsigned short* As = sm;         // dbuf: As + buf*4096
  unsigned short* Bs = sm + 8192;  // dbuf: Bs + buf*4096
  int z = blockIdx.z;
  const unsigned short* B = Wbf + (size_t)z * 589824;
  int mb = blockIdx.x * 128, nb = blockIdx.y * 128;
  int tid = threadIdx.x;
  int w = tid >> 6, lane = tid & 63;
  int wm = w >> 1, wn = w & 1;
  int c = lane & 15, quad = lane >> 4;
  int lrow = lane >> 2;
  int lcol = ((lane & 3) ^ (lrow & 3)) * 8;  // XOR-swizzled source chunk
  const unsigned short* Ag = A + (size_t)(mb + w * 32 + lrow) * 768 + lcol;
  const unsigned short* Bg = B + (size_t)(nb + w * 32 + lrow) * 768 + lcol;
  int woff = w * 1024;

#define PREFETCH(buf, kb)                                              \
  do {                                                                 \
    GLD16(Ag + (kb), As + (buf) * 4096 + woff);                        \
    GLD16(Ag + (kb) + 16 * 768, As + (buf) * 4096 + woff + 512);       \
    GLD16(Bg + (kb), Bs + (buf) * 4096 + woff);                        \
    GLD16(Bg + (kb) + 16 * 768, Bs + (buf) * 4096 + woff + 512);       \
  } while (0)

  f32x4 acc[4][4];
#pragma unroll
  for (int i = 0; i < 4; i++)
#pragma unroll
    for (int j = 0; j < 4; j++) acc[i][j] = 0;

  PREFETCH(0, 0);
  for (int it = 0; it < 24; it++) {
    __syncthreads();
    if (it + 1 < 24) PREFETCH((it + 1) & 1, (it + 1) * 32);
    const unsigned short* Ab = As + (it & 1) * 4096;
    const unsigned short* Bb = Bs + (it & 1) * 4096;
    int sw = (quad ^ (c & 3)) * 8;  // swizzled chunk offset for k-chunk `quad`
    bf16x8 af[4], bfr[4];
#pragma unroll
    for (int i = 0; i < 4; i++)
      af[i] = *(const bf16x8*)&Ab[(wm * 64 + i * 16 + c) * 32 + sw];
#pragma unroll
    for (int j = 0; j < 4; j++)
      bfr[j] = *(const bf16x8*)&Bb[(wn * 64 + j * 16 + c) * 32 + sw];
#pragma unroll
    for (int i = 0; i < 4; i++)
#pragma unroll
      for (int j = 0; j < 4; j++)
        acc[i][j] = __builtin_amdgcn_mfma_f32_16x16x32_bf16(af[i], bfr[j],
                                                            acc[i][j], 0, 0, 0);
  }
  __syncthreads();  // staging reads done before epilogue reuses sm

  // C row = mb+wm*64+i*16+quad*4+r, col = nb+wn*64+j*16+c
  if (z == 2) {
#pragma unroll
    for (int i = 0; i < 4; i++)
#pragma unroll
      for (int j = 0; j < 4; j++)
#pragma unroll
        for (int r = 0; r < 4; r++) {
          int rl = wm * 64 + i * 16 + quad * 4 + r;
          int cl = wn * 64 + j * 16 + c;
          sm[rl * 136 + cl] = f2bf(acc[i][j][r]);
        }
    __syncthreads();
#pragma unroll
    for (int it2 = 0; it2 < 8; it2++) {
      int g2 = it2 * 256 + tid;  // 0..2047, 16B units (128 rows x 16)
      int rl = g2 >> 4;
      int cu = (g2 & 15) * 8;
      bf16x8 vdat = *(const bf16x8*)&sm[rl * 136 + cu];
      *(bf16x8*)&Vbf[(size_t)(mb + rl) * 768 + nb + cu] = vdat;
    }
  } else {
    unsigned short* O = (z == 0) ? Qf : Kf;
#pragma unroll
    for (int i = 0; i < 4; i++) {
#pragma unroll
      for (int r = 0; r < 4; r++) {
        int qlr = wm * 64 + i * 16 + quad * 4 + r;  // 0..127
        int chunkL = (qlr >> 5) * 8 + (c & 7);      // 0..31
        int lane32 = (qlr & 31) + wn * 32;
        ushort4 pk;
        pk.x = f2bf(acc[i][0][r]);
        pk.y = f2bf(acc[i][1][r]);
        pk.z = f2bf(acc[i][2][r]);
        pk.w = f2bf(acc[i][3][r]);
        *(ushort4*)&sm[chunkL * 520 + lane32 * 8 + 4 * (c >> 3)] = pk;
      }
    }
    __syncthreads();
    int bq = mb >> 10;
    int qt32g0 = (mb & 1023) >> 5;
    int tt = blockIdx.y;  // d/16 chunk (0..5)
#pragma unroll
    for (int it2 = 0; it2 < 8; it2++) {
      int g = it2 * 256 + tid;
      int chunkL = g >> 6;
      int off = (g & 63) * 8;
      bf16x8 vdat = *(const bf16x8*)&sm[chunkL * 520 + off];
      int qt32 = qt32g0 + (chunkL >> 3), h = chunkL & 7;
      size_t dst = ((((size_t)(bq * 32 + qt32) * 8 + h) * 6 + tt) << 9) + off;
      *(bf16x8*)&O[dst] = vdat;
    }
  }
#undef PREFETCH
}

// ---------------------------------------------------------------------------
// K4: attention (R8 winner + XCD pinning). Block = 64q x 64k x 8h, 4 waves
// (2x2 of 32x32 via mfma_f32_32x32x16_bf16), barrier-free direct global->VGPR
// fragment loads, h-softmax without max-shift.
// Grid: 2048 linear; b = id&7 so round-robin XCD dispatch pins each batch b
// to one XCD -> Q/K slabs (3.1MB/batch) stay L2-resident (4MB/XCD).
// ---------------------------------------------------------------------------
__global__ __launch_bounds__(256) void attn(
    const unsigned short* __restrict__ Qf, const unsigned short* __restrict__ Kf,
    const float* __restrict__ aw, float* __restrict__ Ptp) {
  __shared__ float pbuf[1024];  // (wq*2+wk)*256 + kcol*8 + h
  int id = blockIdx.x;
  int b = id & 7, qb = (id >> 3) & 15, kb = id >> 7;
  int tid = threadIdx.x, w = tid >> 6, lane = tid & 63;
  int wq = w >> 1, wk = w & 1;
  const unsigned short* Qb =
      Qf + ((size_t)(b * 32 + qb * 2 + wq) * 48) * 512 + (size_t)lane * 8;
  const unsigned short* Kb =
      Kf + ((size_t)(b * 32 + kb * 2 + wk) * 48) * 512 + (size_t)lane * 8;

  f32x16 acc[8];
#pragma unroll
  for (int h = 0; h < 8; h++) acc[h] = 0;
#pragma unroll
  for (int h = 0; h < 8; h++) {
#pragma unroll
    for (int t = 0; t < 6; t++) {
      bf16x8 a = *(const bf16x8*)(Qb + (size_t)(h * 6 + t) * 512);
      bf16x8 bb = *(const bf16x8*)(Kb + (size_t)(h * 6 + t) * 512);
      acc[h] = __builtin_amdgcn_mfma_f32_32x32x16_bf16(a, bb, acc[h], 0, 0, 0);
    }
  }

  // softmax over h per (q,k); C/D: col=lane&31 (k), row=(reg&3)+8*(reg>>2)+4*(lane>>5)
  float awv[16];
#pragma unroll
  for (int reg = 0; reg < 16; reg++) {
    int row = (reg & 3) + 8 * (reg >> 2) + 4 * (lane >> 5);
    awv[reg] = aw[b * 1024 + qb * 64 + wq * 32 + row];
  }
  float partial[8];
#pragma unroll
  for (int h = 0; h < 8; h++) partial[h] = 0.f;
  const float C2 = 0.10206207261596577f * 1.4426950408889634f;  // /sqrt(96)*log2e
#pragma unroll
  for (int reg = 0; reg < 16; reg++) {
    float v[8];
    float ssum = 0.f;
#pragma unroll
    for (int h = 0; h < 8; h++) {
      float e = exp2f(acc[h][reg] * C2);  // no max-shift needed
      v[h] = e;
      ssum += e;
    }
    float g = awv[reg] * __builtin_amdgcn_rcpf(ssum);  // aw==0 for padded q
#pragma unroll
    for (int h = 0; h < 8; h++) partial[h] += v[h] * g;
  }
#pragma unroll
  for (int h = 0; h < 8; h++) {
    float v = partial[h];
    v += __shfl_xor(v, 32);  // combine row halves -> full 32-q sum per col
    partial[h] = v;
  }
  if (lane < 32) {
#pragma unroll
    for (int h = 0; h < 8; h++) pbuf[w * 256 + lane * 8 + h] = partial[h];
  }
  __syncthreads();
  // 256 threads each write BOTH wk halves (512 outputs total)
#pragma unroll
  for (int wk2 = 0; wk2 < 2; wk2++) {
    float s = pbuf[wk2 * 256 + tid] + pbuf[(2 + wk2) * 256 + tid];
    int kcol = tid >> 3, h = tid & 7;
    Ptp[(((size_t)qb * 8 + b) * 1024 + kb * 64 + wk2 * 32 + kcol) * 8 + h] = s;
  }
}

// ---------------------------------------------------------------------------
// K5: out[b,o] = sum_k (sum_qb Ptp[qb][b][k][o&7]) * V[b,k,o]   (V bf16)
// grid (32 kc, 8 b); threads 0..191 each own 4 consecutive o (ushort4 loads)
// ---------------------------------------------------------------------------
__global__ __launch_bounds__(256) void finalize(
    const float* __restrict__ Ptp, const unsigned short* __restrict__ Vbf,
    float* __restrict__ out) {
  __shared__ float ps[256];  // 32 k x 8 h
  int kc = blockIdx.x, b = blockIdx.y;
  int t = threadIdx.x;
  {
    int k = kc * 32 + (t >> 3), h = t & 7;
    float s = 0.f;
#pragma unroll
    for (int qc = 0; qc < 16; qc++)
      s += Ptp[(((size_t)qc * 8 + b) * 1024 + k) * 8 + h];
    ps[t] = s;
  }
  __syncthreads();
  if (t < 192) {
    int o0 = t * 4;
    int hb = o0 & 7;  // 0 or 4
    float a0 = 0, a1 = 0, a2 = 0, a3 = 0;
    const unsigned short* Vb = Vbf + ((size_t)b * 1024 + kc * 32) * 768 + o0;
#pragma unroll 4
    for (int kk = 0; kk < 32; kk++) {
      ushort4 vv = *(const ushort4*)(Vb + (size_t)kk * 768);
      const float* p = &ps[kk * 8 + hb];
      a0 += p[0] * bf2f(vv.x);
      a1 += p[1] * bf2f(vv.y);
      a2 += p[2] * bf2f(vv.z);
      a3 += p[3] * bf2f(vv.w);
    }
    atomicAdd(&out[b * 768 + o0], a0);
    atomicAdd(&out[b * 768 + o0 + 1], a1);
    atomicAdd(&out[b * 768 + o0 + 2], a2);
    atomicAdd(&out[b * 768 + o0 + 3], a3);
  }
}

// ---------------------------------------------------------------------------
extern "C" void kernel_launch(void* const* d_in, const int* in_sizes, int n_in,
                              void* d_out, int out_size, void* d_ws,
                              size_t ws_size, hipStream_t stream) {
  const float* emb = (const float*)d_in[0];
  const int* tags = (const int*)d_in[1];
  const float* ww = (const float*)d_in[2];
  const float* wq = (const float*)d_in[3];
  const float* wk = (const float*)d_in[4];
  const float* wv = (const float*)d_in[5];
  float* out = (float*)d_out;
  char* ws = (char*)d_ws;
  unsigned short* embbf = (unsigned short*)(ws + 0);           // 12,582,912
  unsigned short* wbf   = (unsigned short*)(ws + 12582912);    //  3,538,944
  unsigned short* Qf    = (unsigned short*)(ws + 16121856);    // 12,582,912
  unsigned short* Kf    = (unsigned short*)(ws + 28704768);    // 12,582,912
  unsigned short* Vbf   = (unsigned short*)(ws + 41287680);    // 12,582,912
  float* logits         = (float*)(ws + 53870592);             //     32,768
  float* aw             = (float*)(ws + 53903360);             //     32,768
  float* Ptp            = (float*)(ws + 53936128);             //  4,194,304

  hipMemsetAsync(out, 0, 8 * 768 * sizeof(float), stream);
  cast_inputs<<<3776, 256, 0, stream>>>(emb, tags, ww, wq, wk, wv, embbf,
                                        logits, wbf);
  softmax_aw<<<8, 256, 0, stream>>>(logits, aw);
  qkv_gemm<<<dim3(64, 6, 3), 256, 0, stream>>>(embbf, wbf, Qf, Kf, Vbf);
  attn<<<2048, 256, 0, stream>>>(Qf, Kf, aw, Ptp);
  finalize<<<dim3(32, 8), 256, 0, stream>>>(Ptp, Vbf, out);
}